// Round 2
// baseline (1290.790 us; speedup 1.0000x reference)
//
#include <hip/hip_runtime.h>

#define S_IMG 2304
#define S_TXT 512
#define S_ALL 2816
#define DMODEL 3072
#define NH 24
#define HD 128
#define N3 9216

typedef _Float16 half8 __attribute__((ext_vector_type(8)));
typedef _Float16 half4 __attribute__((ext_vector_type(4)));
typedef _Float16 half2v __attribute__((ext_vector_type(2)));
typedef float float4v __attribute__((ext_vector_type(4)));

__device__ __forceinline__ void gld_lds16(const _Float16* g, _Float16* l) {
  __builtin_amdgcn_global_load_lds(
      (const __attribute__((address_space(1))) unsigned int*)g,
      (__attribute__((address_space(3))) unsigned int*)l, 16, 0, 0);
}

__device__ __forceinline__ float4v mfma16(half8 a, half8 b, float4v c) {
  return __builtin_amdgcn_mfma_f32_16x16x32_f16(a, b, c, 0, 0, 0);
}

// ---------------- cast fp32 -> fp16, 8 elems/thread ----------------
__global__ __launch_bounds__(256) void cast_f32_f16(const float* __restrict__ src,
                                                    _Float16* __restrict__ dst, int n8) {
  int i = blockIdx.x * 256 + threadIdx.x;
  if (i >= n8) return;
  float4v a = ((const float4v*)src)[2 * i];
  float4v b = ((const float4v*)src)[2 * i + 1];
  half8 h;
  h[0] = (_Float16)a[0]; h[1] = (_Float16)a[1]; h[2] = (_Float16)a[2]; h[3] = (_Float16)a[3];
  h[4] = (_Float16)b[0]; h[5] = (_Float16)b[1]; h[6] = (_Float16)b[2]; h[7] = (_Float16)b[3];
  ((half8*)dst)[i] = h;
}

// ---------------- C[M][N] = A[M][K] * W[N][K]^T + bias, fp16 in, OT out ------
// m97 structure: 128x128 block tile, 4 waves (2x2 of 64x64), BK=32,
// global_load_lds width=16 staging. M,N multiples of 128; K multiple of 32.
template <typename OT>
__global__ __launch_bounds__(256) void gemm_f16(const _Float16* __restrict__ A,
                                                const _Float16* __restrict__ W,
                                                const float* __restrict__ bias,
                                                OT* __restrict__ C,
                                                int M, int N, int K) {
  __shared__ __align__(16) _Float16 As[128 * 32];
  __shared__ __align__(16) _Float16 Ws[128 * 32];
  const int tid = threadIdx.x;
  const int wave = tid >> 6, lane = tid & 63;
  const int quad = lane >> 4, col = lane & 15;
  const int wm = (wave >> 1) * 64, wn = (wave & 1) * 64;
  const size_t bm = (size_t)blockIdx.y * 128, bn = (size_t)blockIdx.x * 128;
  const _Float16* Ag = A + (bm + (tid >> 2)) * (size_t)K + (tid & 3) * 8;
  const _Float16* Wg = W + (bn + (tid >> 2)) * (size_t)K + (tid & 3) * 8;

  float4v acc[4][4];
#pragma unroll
  for (int mt = 0; mt < 4; mt++)
#pragma unroll
    for (int nt = 0; nt < 4; nt++) acc[mt][nt] = (float4v){0.f, 0.f, 0.f, 0.f};

  for (int k0 = 0; k0 < K; k0 += 32) {
    gld_lds16(Ag + k0, As + tid * 8);
    gld_lds16(Ag + (size_t)64 * K + k0, As + 2048 + tid * 8);
    gld_lds16(Wg + k0, Ws + tid * 8);
    gld_lds16(Wg + (size_t)64 * K + k0, Ws + 2048 + tid * 8);
    __syncthreads();
    half8 af[4], bf[4];
#pragma unroll
    for (int mt = 0; mt < 4; mt++)
      af[mt] = *(const half8*)&As[(wm + mt * 16 + col) * 32 + quad * 8];
#pragma unroll
    for (int nt = 0; nt < 4; nt++)
      bf[nt] = *(const half8*)&Ws[(wn + nt * 16 + col) * 32 + quad * 8];
#pragma unroll
    for (int mt = 0; mt < 4; mt++)
#pragma unroll
      for (int nt = 0; nt < 4; nt++)
        acc[mt][nt] = mfma16(af[mt], bf[nt], acc[mt][nt]);
    __syncthreads();
  }
#pragma unroll
  for (int mt = 0; mt < 4; mt++)
#pragma unroll
    for (int nt = 0; nt < 4; nt++) {
      const size_t gn = bn + wn + nt * 16 + col;
      const float b = bias[gn];
      const size_t gr = bm + wm + mt * 16 + quad * 4;
#pragma unroll
      for (int i = 0; i < 4; i++)
        C[(gr + i) * (size_t)N + gn] = (OT)(acc[mt][nt][i] + b);
    }
}

// ---------------- RMSNorm + RoPE for Q,K: one wave per (s, h) -------------
__global__ __launch_bounds__(256) void rmsrope(const _Float16* __restrict__ QKV,  // [S_ALL][9216] fp16
                                               const float* __restrict__ nq, const float* __restrict__ nk,
                                               const float* __restrict__ naq, const float* __restrict__ nak,
                                               const float* __restrict__ icos, const float* __restrict__ isin,
                                               const float* __restrict__ tcos, const float* __restrict__ tsin,
                                               _Float16* __restrict__ Qh,  // [NH][S_ALL][HD]
                                               _Float16* __restrict__ Kh) {
  const int wg = blockIdx.x * 4 + (threadIdx.x >> 6);
  const int lane = threadIdx.x & 63;
  const int h = wg % NH;
  const int s = wg / NH;
  const bool is_txt = s < S_TXT;
  const float* nwq = is_txt ? naq : nq;
  const float* nwk = is_txt ? nak : nk;
  const int sr = is_txt ? s : s - S_TXT;
  const float* ct = is_txt ? tcos : icos;
  const float* st = is_txt ? tsin : isin;
  const float cs = ct[sr * 64 + lane];
  const float sn = st[sr * 64 + lane];
  const size_t base = (size_t)s * N3 + h * HD + 2 * lane;
  const half2v q2 = *(const half2v*)&QKV[base];
  const half2v k2 = *(const half2v*)&QKV[base + DMODEL];
  const float qx = (float)q2[0], qy = (float)q2[1];
  const float kx = (float)k2[0], ky = (float)k2[1];
  float sq = qx * qx + qy * qy;
  float sk = kx * kx + ky * ky;
#pragma unroll
  for (int m2 = 32; m2 >= 1; m2 >>= 1) {
    sq += __shfl_xor(sq, m2);
    sk += __shfl_xor(sk, m2);
  }
  const float rq = rsqrtf(sq * (1.f / 128.f) + 1e-6f);
  const float rk = rsqrtf(sk * (1.f / 128.f) + 1e-6f);
  float wa = nwq[2 * lane], wb = nwq[2 * lane + 1];
  float a = qx * rq * wa, b = qy * rq * wb;
  half2v qo = {(_Float16)(a * cs - b * sn), (_Float16)(a * sn + b * cs)};
  wa = nwk[2 * lane]; wb = nwk[2 * lane + 1];
  a = kx * rk * wa; b = ky * rk * wb;
  half2v ko = {(_Float16)(a * cs - b * sn), (_Float16)(a * sn + b * cs)};
  const size_t ob = ((size_t)h * S_ALL + s) * HD + 2 * lane;
  *(half2v*)&Qh[ob] = qo;
  *(half2v*)&Kh[ob] = ko;
}

// ---------------- V: fp16 [S_ALL][9216] (col offset pre-applied) -> fp16 [NH][HD][S_ALL]
__global__ __launch_bounds__(256) void v_transpose(const _Float16* __restrict__ Vraw,
                                                   _Float16* __restrict__ Vt) {
  __shared__ _Float16 T[64][72];
  const int t = threadIdx.x;
  const int sb = blockIdx.x, db = blockIdx.y, h = blockIdx.z;
  const _Float16* src = Vraw + (size_t)(sb * 64) * N3 + h * HD + db * 64;
#pragma unroll
  for (int it = 0; it < 4; it++) {
    int r = it * 16 + (t >> 4);
    int c = (t & 15) * 4;
    *(half4*)&T[r][c] = *(const half4*)(src + (size_t)r * N3 + c);
  }
  __syncthreads();
  _Float16* dst = Vt + ((size_t)h * HD + db * 64) * S_ALL + sb * 64;
#pragma unroll
  for (int it = 0; it < 4; it++) {
    int r = it * 16 + (t >> 4);  // d
    int c = (t & 15) * 4;        // s
    half4 o;
    o[0] = T[c][r]; o[1] = T[c + 1][r];
    o[2] = T[c + 2][r]; o[3] = T[c + 3][r];
    *(half4*)(dst + (size_t)r * S_ALL + c) = o;
  }
}

// ---------------- flash attention: block = (head, 64 q rows), 4 waves x 16 rows
__global__ __launch_bounds__(256) void attn_kernel(const _Float16* __restrict__ Qh,
                                                   const _Float16* __restrict__ Kh,
                                                   const _Float16* __restrict__ Vt,
                                                   _Float16* __restrict__ O) {  // [S_ALL][DMODEL]
  __shared__ __align__(16) _Float16 Qs[64 * 128];
  __shared__ __align__(16) _Float16 Ks[64 * 128];
  __shared__ __align__(16) _Float16 Vs[128 * 64];
  __shared__ __align__(16) _Float16 Ps[4][16 * 72];  // +8 pad breaks write conflicts
  const int tid = threadIdx.x;
  const int wave = tid >> 6, lane = tid & 63;
  const int quad = lane >> 4, col = lane & 15;
  const int h = blockIdx.y;
  const int q0 = blockIdx.x * 64;
  const _Float16* Qg = Qh + ((size_t)h * S_ALL + q0) * HD;
  const _Float16* Kg = Kh + (size_t)h * S_ALL * HD;
  const _Float16* Vg = Vt + (size_t)h * HD * S_ALL;

#pragma unroll
  for (int j = 0; j < 4; j++)
    gld_lds16(Qg + (size_t)(j * 16 + (tid >> 4)) * HD + (tid & 15) * 8, Qs + j * 2048 + tid * 8);
  __syncthreads();
  half8 qf[4];
#pragma unroll
  for (int ks = 0; ks < 4; ks++)
    qf[ks] = *(const half8*)&Qs[(wave * 16 + col) * HD + ks * 32 + quad * 8];

  float m_i[4], l_i[4];
#pragma unroll
  for (int i = 0; i < 4; i++) { m_i[i] = -1e30f; l_i[i] = 0.f; }
  float4v oacc[8];
#pragma unroll
  for (int nt = 0; nt < 8; nt++) oacc[nt] = (float4v){0.f, 0.f, 0.f, 0.f};

  const float sc = 0.08838834764831845f * 1.4426950408889634f;  // 1/sqrt(128) * log2(e)

  for (int kt = 0; kt < S_ALL / 64; kt++) {
    if (kt > 0) __syncthreads();
    const int base = kt * 64;
#pragma unroll
    for (int j = 0; j < 4; j++) {
      gld_lds16(Kg + (size_t)(base + j * 16 + (tid >> 4)) * HD + (tid & 15) * 8,
                Ks + j * 2048 + tid * 8);
      gld_lds16(Vg + (size_t)(j * 32 + (tid >> 3)) * S_ALL + base + (tid & 7) * 8,
                Vs + j * 2048 + tid * 8);
    }
    __syncthreads();

    // S = Q K^T (scaled into exp2 domain)
    float4v sf[4];
#pragma unroll
    for (int nt = 0; nt < 4; nt++) {
      float4v a = (float4v){0.f, 0.f, 0.f, 0.f};
#pragma unroll
      for (int ks = 0; ks < 4; ks++) {
        half8 kf = *(const half8*)&Ks[(nt * 16 + col) * HD + ks * 32 + quad * 8];
        a = mfma16(qf[ks], kf, a);
      }
      sf[nt] = a;
    }
#pragma unroll
    for (int nt = 0; nt < 4; nt++)
#pragma unroll
      for (int i = 0; i < 4; i++) sf[nt][i] *= sc;

    float mnew[4], alpha[4];
#pragma unroll
    for (int i = 0; i < 4; i++) {
      float r = fmaxf(fmaxf(sf[0][i], sf[1][i]), fmaxf(sf[2][i], sf[3][i]));
      r = fmaxf(r, __shfl_xor(r, 1));
      r = fmaxf(r, __shfl_xor(r, 2));
      r = fmaxf(r, __shfl_xor(r, 4));
      r = fmaxf(r, __shfl_xor(r, 8));
      mnew[i] = fmaxf(m_i[i], r);
      alpha[i] = exp2f(m_i[i] - mnew[i]);
      m_i[i] = mnew[i];
    }
#pragma unroll
    for (int nt = 0; nt < 4; nt++)
#pragma unroll
      for (int i = 0; i < 4; i++) sf[nt][i] = exp2f(sf[nt][i] - mnew[i]);
#pragma unroll
    for (int i = 0; i < 4; i++) {
      float r = sf[0][i] + sf[1][i] + sf[2][i] + sf[3][i];
      r += __shfl_xor(r, 1);
      r += __shfl_xor(r, 2);
      r += __shfl_xor(r, 4);
      r += __shfl_xor(r, 8);
      l_i[i] = l_i[i] * alpha[i] + r;
    }
    // P -> LDS (C-layout -> A-layout round trip, m120 pattern)
    _Float16* Pw = &Ps[wave][0];
#pragma unroll
    for (int nt = 0; nt < 4; nt++)
#pragma unroll
      for (int i = 0; i < 4; i++)
        Pw[(quad * 4 + i) * 72 + nt * 16 + col] = (_Float16)sf[nt][i];
    // rescale O while the writes land
#pragma unroll
    for (int nt = 0; nt < 8; nt++)
#pragma unroll
      for (int i = 0; i < 4; i++) oacc[nt][i] *= alpha[i];
    asm volatile("s_waitcnt lgkmcnt(0)" ::: "memory");
    // O += P V
#pragma unroll
    for (int ks = 0; ks < 2; ks++) {
      half8 pf = *(const half8*)&Ps[wave][col * 72 + ks * 32 + quad * 8];
#pragma unroll
      for (int nt = 0; nt < 8; nt++) {
        half8 vf = *(const half8*)&Vs[(nt * 16 + col) * 64 + ks * 32 + quad * 8];
        oacc[nt] = mfma16(pf, vf, oacc[nt]);
      }
    }
  }
  float inv[4];
#pragma unroll
  for (int i = 0; i < 4; i++) inv[i] = 1.0f / l_i[i];
#pragma unroll
  for (int nt = 0; nt < 8; nt++)
#pragma unroll
    for (int i = 0; i < 4; i++) {
      const int s = q0 + wave * 16 + quad * 4 + i;
      O[(size_t)s * DMODEL + h * HD + nt * 16 + col] = (_Float16)(oacc[nt][i] * inv[i]);
    }
}

extern "C" void kernel_launch(void* const* d_in, const int* in_sizes, int n_in,
                              void* d_out, int out_size, void* d_ws, size_t ws_size,
                              hipStream_t stream) {
  const float* hs   = (const float*)d_in[0];
  const float* ehs  = (const float*)d_in[1];
  const float* wq   = (const float*)d_in[2];
  const float* bq   = (const float*)d_in[3];
  const float* wk   = (const float*)d_in[4];
  const float* bk   = (const float*)d_in[5];
  const float* wv   = (const float*)d_in[6];
  const float* bv   = (const float*)d_in[7];
  const float* waq  = (const float*)d_in[8];
  const float* baq  = (const float*)d_in[9];
  const float* wak  = (const float*)d_in[10];
  const float* bak  = (const float*)d_in[11];
  const float* wav  = (const float*)d_in[12];
  const float* bav  = (const float*)d_in[13];
  const float* nq   = (const float*)d_in[14];
  const float* nk   = (const float*)d_in[15];
  const float* naq  = (const float*)d_in[16];
  const float* nak  = (const float*)d_in[17];
  const float* wo   = (const float*)d_in[18];
  const float* bo   = (const float*)d_in[19];
  const float* wao  = (const float*)d_in[20];
  const float* bao  = (const float*)d_in[21];
  const float* icos = (const float*)d_in[22];
  const float* isin = (const float*)d_in[23];
  const float* tcos = (const float*)d_in[24];
  const float* tsin = (const float*)d_in[25];

  // ---- workspace layout (143.2 MB total, buffers reused via stream order) ----
  char* w = (char*)d_ws;
  _Float16* wbuf = (_Float16*)(w + 0);          // 56,623,104 B: w3 casts; later qh/kh; later out-proj weights
  _Float16* qh   = wbuf;                         // [24][2816][128] fp16 (17.3 MB)
  _Float16* kh   = (_Float16*)(w + 17301504);    // [24][2816][128] fp16
  _Float16* xi   = (_Float16*)(w + 56623104);    // 2304x3072 fp16
  _Float16* xt   = (_Float16*)(w + 70778880);    // 512x3072 fp16
  _Float16* ob   = (_Float16*)(w + 56623104);    // [2816][3072] fp16 (aliases xi/xt, dead by then)
  float*    b3i  = (float*)(w + 73924608);       // 9216 fp32
  float*    b3t  = (float*)(w + 73961472);       // 9216 fp32
  _Float16* qkv  = (_Float16*)(w + 73998336);    // [2816][9216] fp16 (txt rows 0..511)
  _Float16* vt   = (_Float16*)(w + 125902848);   // [24][128][2816] fp16
  // end: 143,204,352 B
  float* out = (float*)d_out;

  const size_t WSZ = (size_t)DMODEL * DMODEL;   // 9437184

  // input casts
  cast_f32_f16<<<3456, 256, 0, stream>>>(hs, xi, 884736);
  cast_f32_f16<<<768, 256, 0, stream>>>(ehs, xt, 196608);
  // biases
  hipMemcpyAsync(b3i, bq, 12288, hipMemcpyDeviceToDevice, stream);
  hipMemcpyAsync(b3i + 3072, bk, 12288, hipMemcpyDeviceToDevice, stream);
  hipMemcpyAsync(b3i + 6144, bv, 12288, hipMemcpyDeviceToDevice, stream);
  hipMemcpyAsync(b3t, baq, 12288, hipMemcpyDeviceToDevice, stream);
  hipMemcpyAsync(b3t + 3072, bak, 12288, hipMemcpyDeviceToDevice, stream);
  hipMemcpyAsync(b3t + 6144, bav, 12288, hipMemcpyDeviceToDevice, stream);

  // img QKV: cast [wq;wk;wv] into wbuf, then GEMM (writes qkv rows 512..2815)
  cast_f32_f16<<<4608, 256, 0, stream>>>(wq, wbuf, WSZ / 8);
  cast_f32_f16<<<4608, 256, 0, stream>>>(wk, wbuf + WSZ, WSZ / 8);
  cast_f32_f16<<<4608, 256, 0, stream>>>(wv, wbuf + 2 * WSZ, WSZ / 8);
  gemm_f16<_Float16><<<dim3(72, 18), 256, 0, stream>>>(xi, wbuf, b3i, qkv + (size_t)512 * N3, 2304, N3, DMODEL);
  // txt QKV: cast [waq;wak;wav] into wbuf (img GEMM done first, stream-ordered)
  cast_f32_f16<<<4608, 256, 0, stream>>>(waq, wbuf, WSZ / 8);
  cast_f32_f16<<<4608, 256, 0, stream>>>(wak, wbuf + WSZ, WSZ / 8);
  cast_f32_f16<<<4608, 256, 0, stream>>>(wav, wbuf + 2 * WSZ, WSZ / 8);
  gemm_f16<_Float16><<<dim3(72, 4), 256, 0, stream>>>(xt, wbuf, b3t, qkv, 512, N3, DMODEL);

  // RMS+RoPE -> qh/kh (reuses wbuf region; w3t cast is dead now)
  rmsrope<<<16896, 256, 0, stream>>>(qkv, nq, nk, naq, nak, icos, isin, tcos, tsin, qh, kh);
  v_transpose<<<dim3(44, 2, 24), 256, 0, stream>>>(qkv + 2 * DMODEL, vt);
  attn_kernel<<<dim3(44, 24), 256, 0, stream>>>(qh, kh, vt, ob);

  // output projections: img rows (512..2815 of ob) -> d_out[0..], txt rows -> after img
  _Float16* wo16 = (_Float16*)(w + 73998336);   // reuse qkv region (dead after attn)
  cast_f32_f16<<<4608, 256, 0, stream>>>(wo, wo16, WSZ / 8);
  gemm_f16<float><<<dim3(24, 18), 256, 0, stream>>>(ob + (size_t)512 * DMODEL, wo16, bo, out, 2304, DMODEL, DMODEL);
  cast_f32_f16<<<4608, 256, 0, stream>>>(wao, wo16, WSZ / 8);
  gemm_f16<float><<<dim3(24, 4), 256, 0, stream>>>(ob, wo16, bao, out + (size_t)2304 * DMODEL, 512, DMODEL, DMODEL);
}

// Round 3
// 1113.250 us; speedup vs baseline: 1.1595x; 1.1595x over previous
//
#include <hip/hip_runtime.h>

#define S_IMG 2304
#define S_TXT 512
#define S_ALL 2816
#define DMODEL 3072
#define NH 24
#define HD 128
#define N3 9216

typedef _Float16 half8 __attribute__((ext_vector_type(8)));
typedef _Float16 half4 __attribute__((ext_vector_type(4)));
typedef _Float16 half2v __attribute__((ext_vector_type(2)));
typedef float float4v __attribute__((ext_vector_type(4)));

__device__ __forceinline__ void gld_lds16(const _Float16* g, _Float16* l) {
  __builtin_amdgcn_global_load_lds(
      (const __attribute__((address_space(1))) unsigned int*)g,
      (__attribute__((address_space(3))) unsigned int*)l, 16, 0, 0);
}

__device__ __forceinline__ float4v mfma16(half8 a, half8 b, float4v c) {
  return __builtin_amdgcn_mfma_f32_16x16x32_f16(a, b, c, 0, 0, 0);
}

// ---------------- cast fp32 -> fp16, 8 elems/thread ----------------
__global__ __launch_bounds__(256) void cast_f32_f16(const float* __restrict__ src,
                                                    _Float16* __restrict__ dst, int n8) {
  int i = blockIdx.x * 256 + threadIdx.x;
  if (i >= n8) return;
  float4v a = ((const float4v*)src)[2 * i];
  float4v b = ((const float4v*)src)[2 * i + 1];
  half8 h;
  h[0] = (_Float16)a[0]; h[1] = (_Float16)a[1]; h[2] = (_Float16)a[2]; h[3] = (_Float16)a[3];
  h[4] = (_Float16)b[0]; h[5] = (_Float16)b[1]; h[6] = (_Float16)b[2]; h[7] = (_Float16)b[3];
  ((half8*)dst)[i] = h;
}

// ---------------- pack 6 bias vectors into b3i/b3t (replaces 6 memcpys) ------
__global__ __launch_bounds__(256) void bias_pack(const float* __restrict__ bq, const float* __restrict__ bk,
                                                 const float* __restrict__ bv, const float* __restrict__ baq,
                                                 const float* __restrict__ bak, const float* __restrict__ bav,
                                                 float* __restrict__ b3i, float* __restrict__ b3t) {
  int i = blockIdx.x * 256 + threadIdx.x;  // 0..18431
  int j = i % 9216;
  const float* src;
  if (i < 9216) src = (j < 3072) ? bq : (j < 6144) ? bk : bv;
  else          src = (j < 3072) ? baq : (j < 6144) ? bak : bav;
  float v = src[j & 3071];
  if (i < 9216) b3i[j] = v; else b3t[j] = v;
}

// ---------------- C[M][N] = A[M][K] * W[N][K]^T + bias, fp16 in, OT out ------
template <typename OT>
__global__ __launch_bounds__(256) void gemm_f16(const _Float16* __restrict__ A,
                                                const _Float16* __restrict__ W,
                                                const float* __restrict__ bias,
                                                OT* __restrict__ C,
                                                int M, int N, int K) {
  __shared__ __align__(16) _Float16 As[128 * 32];
  __shared__ __align__(16) _Float16 Ws[128 * 32];
  const int tid = threadIdx.x;
  const int wave = tid >> 6, lane = tid & 63;
  const int quad = lane >> 4, col = lane & 15;
  const int wm = (wave >> 1) * 64, wn = (wave & 1) * 64;
  const size_t bm = (size_t)blockIdx.y * 128, bn = (size_t)blockIdx.x * 128;
  const _Float16* Ag = A + (bm + (tid >> 2)) * (size_t)K + (tid & 3) * 8;
  const _Float16* Wg = W + (bn + (tid >> 2)) * (size_t)K + (tid & 3) * 8;

  float4v acc[4][4];
#pragma unroll
  for (int mt = 0; mt < 4; mt++)
#pragma unroll
    for (int nt = 0; nt < 4; nt++) acc[mt][nt] = (float4v){0.f, 0.f, 0.f, 0.f};

  for (int k0 = 0; k0 < K; k0 += 32) {
    gld_lds16(Ag + k0, As + tid * 8);
    gld_lds16(Ag + (size_t)64 * K + k0, As + 2048 + tid * 8);
    gld_lds16(Wg + k0, Ws + tid * 8);
    gld_lds16(Wg + (size_t)64 * K + k0, Ws + 2048 + tid * 8);
    __syncthreads();
    half8 af[4], bf[4];
#pragma unroll
    for (int mt = 0; mt < 4; mt++)
      af[mt] = *(const half8*)&As[(wm + mt * 16 + col) * 32 + quad * 8];
#pragma unroll
    for (int nt = 0; nt < 4; nt++)
      bf[nt] = *(const half8*)&Ws[(wn + nt * 16 + col) * 32 + quad * 8];
#pragma unroll
    for (int mt = 0; mt < 4; mt++)
#pragma unroll
      for (int nt = 0; nt < 4; nt++)
        acc[mt][nt] = mfma16(af[mt], bf[nt], acc[mt][nt]);
    __syncthreads();
  }
#pragma unroll
  for (int mt = 0; mt < 4; mt++)
#pragma unroll
    for (int nt = 0; nt < 4; nt++) {
      const size_t gn = bn + wn + nt * 16 + col;
      const float b = bias[gn];
      const size_t gr = bm + wm + mt * 16 + quad * 4;
#pragma unroll
      for (int i = 0; i < 4; i++)
        C[(gr + i) * (size_t)N + gn] = (OT)(acc[mt][nt][i] + b);
    }
}

// ---------------- RMSNorm + RoPE for Q,K: one wave per (s, h) -------------
// Q additionally scaled by 1/sqrt(HD)*log2(e) so attn scores exit QK^T in
// exp2 domain directly.
__global__ __launch_bounds__(256) void rmsrope(const _Float16* __restrict__ QKV,  // [S_ALL][9216] fp16
                                               const float* __restrict__ nq, const float* __restrict__ nk,
                                               const float* __restrict__ naq, const float* __restrict__ nak,
                                               const float* __restrict__ icos, const float* __restrict__ isin,
                                               const float* __restrict__ tcos, const float* __restrict__ tsin,
                                               _Float16* __restrict__ Qh,  // [NH][S_ALL][HD]
                                               _Float16* __restrict__ Kh) {
  const float SC = 0.08838834764831845f * 1.4426950408889634f;
  const int wg = blockIdx.x * 4 + (threadIdx.x >> 6);
  const int lane = threadIdx.x & 63;
  const int h = wg % NH;
  const int s = wg / NH;
  const bool is_txt = s < S_TXT;
  const float* nwq = is_txt ? naq : nq;
  const float* nwk = is_txt ? nak : nk;
  const int sr = is_txt ? s : s - S_TXT;
  const float* ct = is_txt ? tcos : icos;
  const float* st = is_txt ? tsin : isin;
  const float cs = ct[sr * 64 + lane];
  const float sn = st[sr * 64 + lane];
  const size_t base = (size_t)s * N3 + h * HD + 2 * lane;
  const half2v q2 = *(const half2v*)&QKV[base];
  const half2v k2 = *(const half2v*)&QKV[base + DMODEL];
  const float qx = (float)q2[0], qy = (float)q2[1];
  const float kx = (float)k2[0], ky = (float)k2[1];
  float sq = qx * qx + qy * qy;
  float sk = kx * kx + ky * ky;
#pragma unroll
  for (int m2 = 32; m2 >= 1; m2 >>= 1) {
    sq += __shfl_xor(sq, m2);
    sk += __shfl_xor(sk, m2);
  }
  const float rq = rsqrtf(sq * (1.f / 128.f) + 1e-6f) * SC;
  const float rk = rsqrtf(sk * (1.f / 128.f) + 1e-6f);
  float wa = nwq[2 * lane], wb = nwq[2 * lane + 1];
  float a = qx * rq * wa, b = qy * rq * wb;
  half2v qo = {(_Float16)(a * cs - b * sn), (_Float16)(a * sn + b * cs)};
  wa = nwk[2 * lane]; wb = nwk[2 * lane + 1];
  a = kx * rk * wa; b = ky * rk * wb;
  half2v ko = {(_Float16)(a * cs - b * sn), (_Float16)(a * sn + b * cs)};
  const size_t ob = ((size_t)h * S_ALL + s) * HD + 2 * lane;
  *(half2v*)&Qh[ob] = qo;
  *(half2v*)&Kh[ob] = ko;
}

// ---------------- V: fp16 [S_ALL][9216] (col offset pre-applied) -> fp16 [NH][HD][S_ALL]
__global__ __launch_bounds__(256) void v_transpose(const _Float16* __restrict__ Vraw,
                                                   _Float16* __restrict__ Vt) {
  __shared__ _Float16 T[64][72];
  const int t = threadIdx.x;
  const int sb = blockIdx.x, db = blockIdx.y, h = blockIdx.z;
  const _Float16* src = Vraw + (size_t)(sb * 64) * N3 + h * HD + db * 64;
#pragma unroll
  for (int it = 0; it < 4; it++) {
    int r = it * 16 + (t >> 4);
    int c = (t & 15) * 4;
    *(half4*)&T[r][c] = *(const half4*)(src + (size_t)r * N3 + c);
  }
  __syncthreads();
  _Float16* dst = Vt + ((size_t)h * HD + db * 64) * S_ALL + sb * 64;
#pragma unroll
  for (int it = 0; it < 4; it++) {
    int r = it * 16 + (t >> 4);  // d
    int c = (t & 15) * 4;        // s
    half4 o;
    o[0] = T[c][r]; o[1] = T[c + 1][r];
    o[2] = T[c + 2][r]; o[3] = T[c + 3][r];
    *(half4*)(dst + (size_t)r * S_ALL + c) = o;
  }
}

// ---------------- flash attention: block = (head, 64 q rows), 4 waves x 16 rows
// LDS layouts are K-slabbed ([ks][row][32 halfs]) so every MFMA fragment read
// is a contiguous 1KB block per wave -> conflict-free (GEMM-style).
__global__ __launch_bounds__(256) void attn_kernel(const _Float16* __restrict__ Qh,
                                                   const _Float16* __restrict__ Kh,
                                                   const _Float16* __restrict__ Vt,
                                                   _Float16* __restrict__ O) {  // [S_ALL][DMODEL]
  __shared__ __align__(16) _Float16 Qs[4 * 64 * 32];   // [ks][64 q][32]
  __shared__ __align__(16) _Float16 Ks[4 * 64 * 32];   // [ks][64 k][32]
  __shared__ __align__(16) _Float16 Vs[2 * 128 * 32];  // [ks2][128 d][32 s]
  __shared__ __align__(16) _Float16 Ps[4][16 * 72];
  const int tid = threadIdx.x;
  const int wave = tid >> 6, lane = tid & 63;
  const int quad = lane >> 4, col = lane & 15;
  const int h = blockIdx.y;
  const int q0 = blockIdx.x * 64;
  const _Float16* Qg = Qh + ((size_t)h * S_ALL + q0) * HD;
  const _Float16* Kg = Kh + (size_t)h * S_ALL * HD;
  const _Float16* Vg = Vt + (size_t)h * HD * S_ALL;

  // stage Q into k-slabs: slab j holds cols [j*32, j*32+32) of all 64 rows
#pragma unroll
  for (int j = 0; j < 4; j++)
    gld_lds16(Qg + (size_t)(tid >> 2) * HD + j * 32 + (tid & 3) * 8, Qs + j * 2048 + tid * 8);
  __syncthreads();
  half8 qf[4];
#pragma unroll
  for (int ks = 0; ks < 4; ks++)
    qf[ks] = *(const half8*)&Qs[ks * 2048 + (wave * 16 + col) * 32 + quad * 8];

  float m_i[4], l_i[4];
#pragma unroll
  for (int i = 0; i < 4; i++) { m_i[i] = -1e30f; l_i[i] = 0.f; }
  float4v oacc[8];
#pragma unroll
  for (int nt = 0; nt < 8; nt++) oacc[nt] = (float4v){0.f, 0.f, 0.f, 0.f};

  for (int kt = 0; kt < S_ALL / 64; kt++) {
    if (kt > 0) __syncthreads();
    const int base = kt * 64;
#pragma unroll
    for (int j = 0; j < 4; j++) {
      gld_lds16(Kg + (size_t)(base + (tid >> 2)) * HD + j * 32 + (tid & 3) * 8,
                Ks + j * 2048 + tid * 8);
      gld_lds16(Vg + (size_t)(((j & 1) * 256 + tid) >> 2) * S_ALL + base + (j >> 1) * 32 + (tid & 3) * 8,
                Vs + j * 2048 + tid * 8);
    }
    __syncthreads();

    // S = Q K^T (already in exp2 domain; Q pre-scaled)
    float4v sf[4];
#pragma unroll
    for (int nt = 0; nt < 4; nt++) {
      float4v a = (float4v){0.f, 0.f, 0.f, 0.f};
#pragma unroll
      for (int ks = 0; ks < 4; ks++) {
        half8 kf = *(const half8*)&Ks[ks * 2048 + (nt * 16 + col) * 32 + quad * 8];
        a = mfma16(qf[ks], kf, a);
      }
      sf[nt] = a;
    }

    float mnew[4], alpha[4];
#pragma unroll
    for (int i = 0; i < 4; i++) {
      float r = fmaxf(fmaxf(sf[0][i], sf[1][i]), fmaxf(sf[2][i], sf[3][i]));
      r = fmaxf(r, __shfl_xor(r, 1));
      r = fmaxf(r, __shfl_xor(r, 2));
      r = fmaxf(r, __shfl_xor(r, 4));
      r = fmaxf(r, __shfl_xor(r, 8));
      mnew[i] = fmaxf(m_i[i], r);
      alpha[i] = exp2f(m_i[i] - mnew[i]);
      m_i[i] = mnew[i];
    }
#pragma unroll
    for (int nt = 0; nt < 4; nt++)
#pragma unroll
      for (int i = 0; i < 4; i++) sf[nt][i] = exp2f(sf[nt][i] - mnew[i]);
#pragma unroll
    for (int i = 0; i < 4; i++) {
      float r = sf[0][i] + sf[1][i] + sf[2][i] + sf[3][i];
      r += __shfl_xor(r, 1);
      r += __shfl_xor(r, 2);
      r += __shfl_xor(r, 4);
      r += __shfl_xor(r, 8);
      l_i[i] = l_i[i] * alpha[i] + r;
    }
    // P -> LDS (C-layout -> A-layout round trip)
    _Float16* Pw = &Ps[wave][0];
#pragma unroll
    for (int nt = 0; nt < 4; nt++)
#pragma unroll
      for (int i = 0; i < 4; i++)
        Pw[(quad * 4 + i) * 72 + nt * 16 + col] = (_Float16)sf[nt][i];
    // rescale O while the writes land
#pragma unroll
    for (int nt = 0; nt < 8; nt++)
#pragma unroll
      for (int i = 0; i < 4; i++) oacc[nt][i] *= alpha[i];
    asm volatile("s_waitcnt lgkmcnt(0)" ::: "memory");
    // O += P V
#pragma unroll
    for (int ks = 0; ks < 2; ks++) {
      half8 pf = *(const half8*)&Ps[wave][col * 72 + ks * 32 + quad * 8];
#pragma unroll
      for (int nt = 0; nt < 8; nt++) {
        half8 vf = *(const half8*)&Vs[ks * 4096 + (nt * 16 + col) * 32 + quad * 8];
        oacc[nt] = mfma16(pf, vf, oacc[nt]);
      }
    }
  }
  float inv[4];
#pragma unroll
  for (int i = 0; i < 4; i++) inv[i] = 1.0f / l_i[i];
#pragma unroll
  for (int nt = 0; nt < 8; nt++)
#pragma unroll
    for (int i = 0; i < 4; i++) {
      const int s = q0 + wave * 16 + quad * 4 + i;
      O[(size_t)s * DMODEL + h * HD + nt * 16 + col] = (_Float16)(oacc[nt][i] * inv[i]);
    }
}

extern "C" void kernel_launch(void* const* d_in, const int* in_sizes, int n_in,
                              void* d_out, int out_size, void* d_ws, size_t ws_size,
                              hipStream_t stream) {
  const float* hs   = (const float*)d_in[0];
  const float* ehs  = (const float*)d_in[1];
  const float* wq   = (const float*)d_in[2];
  const float* bq   = (const float*)d_in[3];
  const float* wk   = (const float*)d_in[4];
  const float* bk   = (const float*)d_in[5];
  const float* wv   = (const float*)d_in[6];
  const float* bv   = (const float*)d_in[7];
  const float* waq  = (const float*)d_in[8];
  const float* baq  = (const float*)d_in[9];
  const float* wak  = (const float*)d_in[10];
  const float* bak  = (const float*)d_in[11];
  const float* wav  = (const float*)d_in[12];
  const float* bav  = (const float*)d_in[13];
  const float* nq   = (const float*)d_in[14];
  const float* nk   = (const float*)d_in[15];
  const float* naq  = (const float*)d_in[16];
  const float* nak  = (const float*)d_in[17];
  const float* wo   = (const float*)d_in[18];
  const float* bo   = (const float*)d_in[19];
  const float* wao  = (const float*)d_in[20];
  const float* bao  = (const float*)d_in[21];
  const float* icos = (const float*)d_in[22];
  const float* isin = (const float*)d_in[23];
  const float* tcos = (const float*)d_in[24];
  const float* tsin = (const float*)d_in[25];

  // ---- workspace layout (143.2 MB total, buffers reused via stream order) ----
  char* w = (char*)d_ws;
  _Float16* wbuf = (_Float16*)(w + 0);          // 56.6 MB: w3 casts; later qh/kh
  _Float16* qh   = wbuf;                         // [24][2816][128] fp16
  _Float16* kh   = (_Float16*)(w + 17301504);
  _Float16* xi   = (_Float16*)(w + 56623104);    // 2304x3072 fp16
  _Float16* xt   = (_Float16*)(w + 70778880);    // 512x3072 fp16
  _Float16* ob   = (_Float16*)(w + 56623104);    // [2816][3072] fp16 (aliases xi/xt)
  float*    b3i  = (float*)(w + 73924608);
  float*    b3t  = (float*)(w + 73961472);
  _Float16* qkv  = (_Float16*)(w + 73998336);    // [2816][9216] fp16 (txt rows 0..511)
  _Float16* vt   = (_Float16*)(w + 125902848);   // [24][128][2816] fp16
  float* out = (float*)d_out;

  const size_t WSZ = (size_t)DMODEL * DMODEL;   // 9437184

  cast_f32_f16<<<3456, 256, 0, stream>>>(hs, xi, 884736);
  cast_f32_f16<<<768, 256, 0, stream>>>(ehs, xt, 196608);
  bias_pack<<<72, 256, 0, stream>>>(bq, bk, bv, baq, bak, bav, b3i, b3t);

  // img QKV
  cast_f32_f16<<<4608, 256, 0, stream>>>(wq, wbuf, WSZ / 8);
  cast_f32_f16<<<4608, 256, 0, stream>>>(wk, wbuf + WSZ, WSZ / 8);
  cast_f32_f16<<<4608, 256, 0, stream>>>(wv, wbuf + 2 * WSZ, WSZ / 8);
  gemm_f16<_Float16><<<dim3(72, 18), 256, 0, stream>>>(xi, wbuf, b3i, qkv + (size_t)512 * N3, 2304, N3, DMODEL);
  // txt QKV
  cast_f32_f16<<<4608, 256, 0, stream>>>(waq, wbuf, WSZ / 8);
  cast_f32_f16<<<4608, 256, 0, stream>>>(wak, wbuf + WSZ, WSZ / 8);
  cast_f32_f16<<<4608, 256, 0, stream>>>(wav, wbuf + 2 * WSZ, WSZ / 8);
  gemm_f16<_Float16><<<dim3(72, 4), 256, 0, stream>>>(xt, wbuf, b3t, qkv, 512, N3, DMODEL);

  rmsrope<<<16896, 256, 0, stream>>>(qkv, nq, nk, naq, nak, icos, isin, tcos, tsin, qh, kh);
  v_transpose<<<dim3(44, 2, 24), 256, 0, stream>>>(qkv + 2 * DMODEL, vt);
  attn_kernel<<<dim3(44, 24), 256, 0, stream>>>(qh, kh, vt, ob);

  _Float16* wo16 = (_Float16*)(w + 73998336);   // reuse qkv region (dead after attn)
  cast_f32_f16<<<4608, 256, 0, stream>>>(wo, wo16, WSZ / 8);
  gemm_f16<float><<<dim3(24, 18), 256, 0, stream>>>(ob + (size_t)512 * DMODEL, wo16, bo, out, 2304, DMODEL, DMODEL);
  cast_f32_f16<<<4608, 256, 0, stream>>>(wao, wo16, WSZ / 8);
  gemm_f16<float><<<dim3(24, 4), 256, 0, stream>>>(ob, wo16, bao, out + (size_t)2304 * DMODEL, 512, DMODEL, DMODEL);
}

// Round 4
// 995.877 us; speedup vs baseline: 1.2961x; 1.1179x over previous
//
#include <hip/hip_runtime.h>

#define S_IMG 2304
#define S_TXT 512
#define S_ALL 2816
#define DMODEL 3072
#define NH 24
#define HD 128
#define N3 9216

typedef _Float16 half8 __attribute__((ext_vector_type(8)));
typedef _Float16 half4 __attribute__((ext_vector_type(4)));
typedef _Float16 half2v __attribute__((ext_vector_type(2)));
typedef float float4v __attribute__((ext_vector_type(4)));

__device__ __forceinline__ void gld_lds16(const _Float16* g, _Float16* l) {
  __builtin_amdgcn_global_load_lds(
      (const __attribute__((address_space(1))) unsigned int*)g,
      (__attribute__((address_space(3))) unsigned int*)l, 16, 0, 0);
}

__device__ __forceinline__ float4v mfma16(half8 a, half8 b, float4v c) {
  return __builtin_amdgcn_mfma_f32_16x16x32_f16(a, b, c, 0, 0, 0);
}

// ---------------- cast fp32 -> fp16, 8 elems/thread ----------------
__global__ __launch_bounds__(256) void cast_f32_f16(const float* __restrict__ src,
                                                    _Float16* __restrict__ dst, int n8) {
  int i = blockIdx.x * 256 + threadIdx.x;
  if (i >= n8) return;
  float4v a = ((const float4v*)src)[2 * i];
  float4v b = ((const float4v*)src)[2 * i + 1];
  half8 h;
  h[0] = (_Float16)a[0]; h[1] = (_Float16)a[1]; h[2] = (_Float16)a[2]; h[3] = (_Float16)a[3];
  h[4] = (_Float16)b[0]; h[5] = (_Float16)b[1]; h[6] = (_Float16)b[2]; h[7] = (_Float16)b[3];
  ((half8*)dst)[i] = h;
}

// ---------------- pack 6 bias vectors into b3i/b3t ----------------
__global__ __launch_bounds__(256) void bias_pack(const float* __restrict__ bq, const float* __restrict__ bk,
                                                 const float* __restrict__ bv, const float* __restrict__ baq,
                                                 const float* __restrict__ bak, const float* __restrict__ bav,
                                                 float* __restrict__ b3i, float* __restrict__ b3t) {
  int i = blockIdx.x * 256 + threadIdx.x;  // 0..18431
  int j = i % 9216;
  const float* src;
  if (i < 9216) src = (j < 3072) ? bq : (j < 6144) ? bk : bv;
  else          src = (j < 3072) ? baq : (j < 6144) ? bak : bav;
  float v = src[j & 3071];
  if (i < 9216) b3i[j] = v; else b3t[j] = v;
}

// ---------------- C[M][N] = A[M][K] * W[N][K]^T + bias, fp16 in, OT out ------
template <typename OT>
__global__ __launch_bounds__(256) void gemm_f16(const _Float16* __restrict__ A,
                                                const _Float16* __restrict__ W,
                                                const float* __restrict__ bias,
                                                OT* __restrict__ C,
                                                int M, int N, int K) {
  __shared__ __align__(16) _Float16 As[128 * 32];
  __shared__ __align__(16) _Float16 Ws[128 * 32];
  const int tid = threadIdx.x;
  const int wave = tid >> 6, lane = tid & 63;
  const int quad = lane >> 4, col = lane & 15;
  const int wm = (wave >> 1) * 64, wn = (wave & 1) * 64;
  const size_t bm = (size_t)blockIdx.y * 128, bn = (size_t)blockIdx.x * 128;
  const _Float16* Ag = A + (bm + (tid >> 2)) * (size_t)K + (tid & 3) * 8;
  const _Float16* Wg = W + (bn + (tid >> 2)) * (size_t)K + (tid & 3) * 8;

  float4v acc[4][4];
#pragma unroll
  for (int mt = 0; mt < 4; mt++)
#pragma unroll
    for (int nt = 0; nt < 4; nt++) acc[mt][nt] = (float4v){0.f, 0.f, 0.f, 0.f};

  for (int k0 = 0; k0 < K; k0 += 32) {
    gld_lds16(Ag + k0, As + tid * 8);
    gld_lds16(Ag + (size_t)64 * K + k0, As + 2048 + tid * 8);
    gld_lds16(Wg + k0, Ws + tid * 8);
    gld_lds16(Wg + (size_t)64 * K + k0, Ws + 2048 + tid * 8);
    __syncthreads();
    half8 af[4], bf[4];
#pragma unroll
    for (int mt = 0; mt < 4; mt++)
      af[mt] = *(const half8*)&As[(wm + mt * 16 + col) * 32 + quad * 8];
#pragma unroll
    for (int nt = 0; nt < 4; nt++)
      bf[nt] = *(const half8*)&Ws[(wn + nt * 16 + col) * 32 + quad * 8];
#pragma unroll
    for (int mt = 0; mt < 4; mt++)
#pragma unroll
      for (int nt = 0; nt < 4; nt++)
        acc[mt][nt] = mfma16(af[mt], bf[nt], acc[mt][nt]);
    __syncthreads();
  }
#pragma unroll
  for (int mt = 0; mt < 4; mt++)
#pragma unroll
    for (int nt = 0; nt < 4; nt++) {
      const size_t gn = bn + wn + nt * 16 + col;
      const float b = bias[gn];
      const size_t gr = bm + wm + mt * 16 + quad * 4;
#pragma unroll
      for (int i = 0; i < 4; i++)
        C[(gr + i) * (size_t)N + gn] = (OT)(acc[mt][nt][i] + b);
    }
}

// ---------------- RMSNorm + RoPE for Q,K: one wave per (s, h) -------------
// Q additionally scaled by 1/sqrt(HD)*log2(e) so QK^T exits in exp2 domain.
__global__ __launch_bounds__(256) void rmsrope(const _Float16* __restrict__ QKV,  // [S_ALL][9216] fp16
                                               const float* __restrict__ nq, const float* __restrict__ nk,
                                               const float* __restrict__ naq, const float* __restrict__ nak,
                                               const float* __restrict__ icos, const float* __restrict__ isin,
                                               const float* __restrict__ tcos, const float* __restrict__ tsin,
                                               _Float16* __restrict__ Qh,  // [NH][S_ALL][HD]
                                               _Float16* __restrict__ Kh) {
  const float SC = 0.08838834764831845f * 1.4426950408889634f;
  const int wg = blockIdx.x * 4 + (threadIdx.x >> 6);
  const int lane = threadIdx.x & 63;
  const int h = wg % NH;
  const int s = wg / NH;
  const bool is_txt = s < S_TXT;
  const float* nwq = is_txt ? naq : nq;
  const float* nwk = is_txt ? nak : nk;
  const int sr = is_txt ? s : s - S_TXT;
  const float* ct = is_txt ? tcos : icos;
  const float* st = is_txt ? tsin : isin;
  const float cs = ct[sr * 64 + lane];
  const float sn = st[sr * 64 + lane];
  const size_t base = (size_t)s * N3 + h * HD + 2 * lane;
  const half2v q2 = *(const half2v*)&QKV[base];
  const half2v k2 = *(const half2v*)&QKV[base + DMODEL];
  const float qx = (float)q2[0], qy = (float)q2[1];
  const float kx = (float)k2[0], ky = (float)k2[1];
  float sq = qx * qx + qy * qy;
  float sk = kx * kx + ky * ky;
#pragma unroll
  for (int m2 = 32; m2 >= 1; m2 >>= 1) {
    sq += __shfl_xor(sq, m2);
    sk += __shfl_xor(sk, m2);
  }
  const float rq = rsqrtf(sq * (1.f / 128.f) + 1e-6f) * SC;
  const float rk = rsqrtf(sk * (1.f / 128.f) + 1e-6f);
  float wa = nwq[2 * lane], wb = nwq[2 * lane + 1];
  float a = qx * rq * wa, b = qy * rq * wb;
  half2v qo = {(_Float16)(a * cs - b * sn), (_Float16)(a * sn + b * cs)};
  wa = nwk[2 * lane]; wb = nwk[2 * lane + 1];
  a = kx * rk * wa; b = ky * rk * wb;
  half2v ko = {(_Float16)(a * cs - b * sn), (_Float16)(a * sn + b * cs)};
  const size_t ob = ((size_t)h * S_ALL + s) * HD + 2 * lane;
  *(half2v*)&Qh[ob] = qo;
  *(half2v*)&Kh[ob] = ko;
}

// ---------------- V: fp16 [S_ALL][9216] (col offset pre-applied) -> fp16 [NH][HD][S_ALL]
__global__ __launch_bounds__(256) void v_transpose(const _Float16* __restrict__ Vraw,
                                                   _Float16* __restrict__ Vt) {
  __shared__ _Float16 T[64][72];
  const int t = threadIdx.x;
  const int sb = blockIdx.x, db = blockIdx.y, h = blockIdx.z;
  const _Float16* src = Vraw + (size_t)(sb * 64) * N3 + h * HD + db * 64;
#pragma unroll
  for (int it = 0; it < 4; it++) {
    int r = it * 16 + (t >> 4);
    int c = (t & 15) * 4;
    *(half4*)&T[r][c] = *(const half4*)(src + (size_t)r * N3 + c);
  }
  __syncthreads();
  _Float16* dst = Vt + ((size_t)h * HD + db * 64) * S_ALL + sb * 64;
#pragma unroll
  for (int it = 0; it < 4; it++) {
    int r = it * 16 + (t >> 4);  // d
    int c = (t & 15) * 4;        // s
    half4 o;
    o[0] = T[c][r]; o[1] = T[c + 1][r];
    o[2] = T[c + 2][r]; o[3] = T[c + 3][r];
    *(half4*)(dst + (size_t)r * S_ALL + c) = o;
  }
}

// ---------------- flash attention v3 ----------------
// Block = (head, 64 q rows), 4 waves x 16 q-rows. Max-free softmax (scores
// hard-bounded: |q|=|k|=sqrt(128) after RMS => s*log2e <= 16.3; fixed offset 2
// cancels in p/l). No Q LDS (frags from global). K-slabbed LDS, conflict-free.
// LDS 40KB -> 4 blocks/CU.
__global__ __launch_bounds__(256) void attn_kernel(const _Float16* __restrict__ Qh,
                                                   const _Float16* __restrict__ Kh,
                                                   const _Float16* __restrict__ Vt,
                                                   _Float16* __restrict__ O) {  // [S_ALL][DMODEL]
  __shared__ __align__(16) _Float16 Ks[4 * 64 * 32];   // [ks][64 k][32]   16KB
  __shared__ __align__(16) _Float16 Vs[2 * 128 * 32];  // [ks2][128 d][32] 16KB
  __shared__ __align__(16) _Float16 Ps[4][2][16 * 32]; // [wave][ks2][16q][32k] 8KB
  const int tid = threadIdx.x;
  const int wave = tid >> 6, lane = tid & 63;
  const int quad = lane >> 4, col = lane & 15;
  const int h = blockIdx.y;
  const int q0 = blockIdx.x * 64;
  const _Float16* Qg = Qh + ((size_t)h * S_ALL + q0) * HD;
  const _Float16* Kg = Kh + (size_t)h * S_ALL * HD;
  const _Float16* Vg = Vt + (size_t)h * HD * S_ALL;

  // Q fragments straight from global (one-time)
  half8 qf[4];
#pragma unroll
  for (int ks = 0; ks < 4; ks++)
    qf[ks] = *(const half8*)(Qg + (size_t)(wave * 16 + col) * HD + ks * 32 + quad * 8);

  float l_i[4] = {0.f, 0.f, 0.f, 0.f};  // per-lane partial row sums
  float4v oacc[8];
#pragma unroll
  for (int nt = 0; nt < 8; nt++) oacc[nt] = (float4v){0.f, 0.f, 0.f, 0.f};

  for (int kt = 0; kt < S_ALL / 64; kt++) {
    if (kt > 0) __syncthreads();  // prev iter's Ks/Vs reads complete
    const int base = kt * 64;
#pragma unroll
    for (int j = 0; j < 4; j++) {
      gld_lds16(Kg + (size_t)(base + (tid >> 2)) * HD + j * 32 + (tid & 3) * 8,
                Ks + j * 2048 + tid * 8);
      gld_lds16(Vg + (size_t)(((j & 1) * 256 + tid) >> 2) * S_ALL + base + (j >> 1) * 32 + (tid & 3) * 8,
                Vs + j * 2048 + tid * 8);
    }
    __syncthreads();

    // S = Q K^T (already in exp2 domain; Q pre-scaled)
    float4v sf[4];
#pragma unroll
    for (int nt = 0; nt < 4; nt++) {
      float4v a = (float4v){0.f, 0.f, 0.f, 0.f};
#pragma unroll
      for (int ks = 0; ks < 4; ks++) {
        half8 kf = *(const half8*)&Ks[ks * 2048 + (nt * 16 + col) * 32 + quad * 8];
        a = mfma16(qf[ks], kf, a);
      }
      sf[nt] = a;
    }
    // p = exp2(s - 2); accumulate per-lane row-sum partials (no cross-lane work)
#pragma unroll
    for (int nt = 0; nt < 4; nt++)
#pragma unroll
      for (int i = 0; i < 4; i++) sf[nt][i] = exp2f(sf[nt][i] - 2.0f);
#pragma unroll
    for (int i = 0; i < 4; i++)
      l_i[i] += (sf[0][i] + sf[1][i]) + (sf[2][i] + sf[3][i]);
    // P -> LDS, slab layout: [ks2][16 q][32 k]
    _Float16* Pw = &Ps[wave][0][0];
#pragma unroll
    for (int nt = 0; nt < 4; nt++)
#pragma unroll
      for (int i = 0; i < 4; i++)
        Pw[(nt >> 1) * 512 + (quad * 4 + i) * 32 + (nt & 1) * 16 + col] = (_Float16)sf[nt][i];
    asm volatile("s_waitcnt lgkmcnt(0)" ::: "memory");
    // O += P V
#pragma unroll
    for (int ks = 0; ks < 2; ks++) {
      half8 pf = *(const half8*)&Ps[wave][ks][col * 32 + quad * 8];
#pragma unroll
      for (int nt = 0; nt < 8; nt++) {
        half8 vf = *(const half8*)&Vs[ks * 4096 + (nt * 16 + col) * 32 + quad * 8];
        oacc[nt] = mfma16(pf, vf, oacc[nt]);
      }
    }
  }
  // final l reduction across the 16 lanes sharing a quad (row = quad*4+i)
#pragma unroll
  for (int i = 0; i < 4; i++) {
    l_i[i] += __shfl_xor(l_i[i], 1);
    l_i[i] += __shfl_xor(l_i[i], 2);
    l_i[i] += __shfl_xor(l_i[i], 4);
    l_i[i] += __shfl_xor(l_i[i], 8);
    l_i[i] = 1.0f / l_i[i];
  }
#pragma unroll
  for (int nt = 0; nt < 8; nt++)
#pragma unroll
    for (int i = 0; i < 4; i++) {
      const int s = q0 + wave * 16 + quad * 4 + i;
      O[(size_t)s * DMODEL + h * HD + nt * 16 + col] = (_Float16)(oacc[nt][i] * l_i[i]);
    }
}

extern "C" void kernel_launch(void* const* d_in, const int* in_sizes, int n_in,
                              void* d_out, int out_size, void* d_ws, size_t ws_size,
                              hipStream_t stream) {
  const float* hs   = (const float*)d_in[0];
  const float* ehs  = (const float*)d_in[1];
  const float* wq   = (const float*)d_in[2];
  const float* bq   = (const float*)d_in[3];
  const float* wk   = (const float*)d_in[4];
  const float* bk   = (const float*)d_in[5];
  const float* wv   = (const float*)d_in[6];
  const float* bv   = (const float*)d_in[7];
  const float* waq  = (const float*)d_in[8];
  const float* baq  = (const float*)d_in[9];
  const float* wak  = (const float*)d_in[10];
  const float* bak  = (const float*)d_in[11];
  const float* wav  = (const float*)d_in[12];
  const float* bav  = (const float*)d_in[13];
  const float* nq   = (const float*)d_in[14];
  const float* nk   = (const float*)d_in[15];
  const float* naq  = (const float*)d_in[16];
  const float* nak  = (const float*)d_in[17];
  const float* wo   = (const float*)d_in[18];
  const float* bo   = (const float*)d_in[19];
  const float* wao  = (const float*)d_in[20];
  const float* bao  = (const float*)d_in[21];
  const float* icos = (const float*)d_in[22];
  const float* isin = (const float*)d_in[23];
  const float* tcos = (const float*)d_in[24];
  const float* tsin = (const float*)d_in[25];

  // ---- workspace layout (143.2 MB total, buffers reused via stream order) ----
  char* w = (char*)d_ws;
  _Float16* wbuf = (_Float16*)(w + 0);          // 56.6 MB: w3 casts; later qh/kh
  _Float16* qh   = wbuf;                         // [24][2816][128] fp16
  _Float16* kh   = (_Float16*)(w + 17301504);
  _Float16* xi   = (_Float16*)(w + 56623104);    // 2304x3072 fp16
  _Float16* xt   = (_Float16*)(w + 70778880);    // 512x3072 fp16
  _Float16* ob   = (_Float16*)(w + 56623104);    // [2816][3072] fp16 (aliases xi/xt)
  float*    b3i  = (float*)(w + 73924608);
  float*    b3t  = (float*)(w + 73961472);
  _Float16* qkv  = (_Float16*)(w + 73998336);    // [2816][9216] fp16 (txt rows 0..511)
  _Float16* vt   = (_Float16*)(w + 125902848);   // [24][128][2816] fp16
  float* out = (float*)d_out;

  const size_t WSZ = (size_t)DMODEL * DMODEL;   // 9437184

  cast_f32_f16<<<3456, 256, 0, stream>>>(hs, xi, 884736);
  cast_f32_f16<<<768, 256, 0, stream>>>(ehs, xt, 196608);
  bias_pack<<<72, 256, 0, stream>>>(bq, bk, bv, baq, bak, bav, b3i, b3t);

  // img QKV
  cast_f32_f16<<<4608, 256, 0, stream>>>(wq, wbuf, WSZ / 8);
  cast_f32_f16<<<4608, 256, 0, stream>>>(wk, wbuf + WSZ, WSZ / 8);
  cast_f32_f16<<<4608, 256, 0, stream>>>(wv, wbuf + 2 * WSZ, WSZ / 8);
  gemm_f16<_Float16><<<dim3(72, 18), 256, 0, stream>>>(xi, wbuf, b3i, qkv + (size_t)512 * N3, 2304, N3, DMODEL);
  // txt QKV
  cast_f32_f16<<<4608, 256, 0, stream>>>(waq, wbuf, WSZ / 8);
  cast_f32_f16<<<4608, 256, 0, stream>>>(wak, wbuf + WSZ, WSZ / 8);
  cast_f32_f16<<<4608, 256, 0, stream>>>(wav, wbuf + 2 * WSZ, WSZ / 8);
  gemm_f16<_Float16><<<dim3(72, 4), 256, 0, stream>>>(xt, wbuf, b3t, qkv, 512, N3, DMODEL);

  rmsrope<<<16896, 256, 0, stream>>>(qkv, nq, nk, naq, nak, icos, isin, tcos, tsin, qh, kh);
  v_transpose<<<dim3(44, 2, 24), 256, 0, stream>>>(qkv + 2 * DMODEL, vt);
  attn_kernel<<<dim3(44, 24), 256, 0, stream>>>(qh, kh, vt, ob);

  _Float16* wo16 = (_Float16*)(w + 73998336);   // reuse qkv region (dead after attn)
  cast_f32_f16<<<4608, 256, 0, stream>>>(wo, wo16, WSZ / 8);
  gemm_f16<float><<<dim3(24, 18), 256, 0, stream>>>(ob + (size_t)512 * DMODEL, wo16, bo, out, 2304, DMODEL, DMODEL);
  cast_f32_f16<<<4608, 256, 0, stream>>>(wao, wo16, WSZ / 8);
  gemm_f16<float><<<dim3(24, 4), 256, 0, stream>>>(ob, wo16, bao, out + (size_t)2304 * DMODEL, 512, DMODEL, DMODEL);
}